// Round 14
// baseline (1265.560 us; speedup 1.0000x reference)
//
#include <hip/hip_runtime.h>
#include <cfloat>

#define B_  8
#define N_  2048
#define H_  256
#define L_  4
#define K_  16
#define G_  512
#define M0_ 256
#define M1_ 128
#define C_  128
#define BN_ 16384   // B_*N_
#define KP_ 768     // packed split-bf16 K (3*H_)

typedef unsigned short ushort_t;
typedef __attribute__((ext_vector_type(8))) short short8;
typedef __attribute__((ext_vector_type(4))) float f32x4;

// ---------------- workspace layout (bytes) ----------------
#define OFF_H     ((size_t)0)            // 16 MB  h (fp32, persistent)
#define OFF_APACK ((size_t)16777216)     // 25.2 MB  P-pack [hi,lo,hi] (Q read via seg remap)
#define OFF_CMIN  ((size_t)41943040)     // 4 MB  per-(row,32-col-chunk) minima (BN x 64 f32)
#define OFF_SQ    ((size_t)67108864)     // 64 KB
#define OFF_IDX   ((size_t)67174400)     // 1 MB
#define OFF_STATS ((size_t)68222976)     // 4 KB (512 doubles)
#define OFF_SCSH  ((size_t)68227072)     // 2 KB
#define OFF_BCAT  ((size_t)68229120)     // 2 KB
#define OFF_P0    ((size_t)68231168)     // 16 KB
#define OFF_P1    ((size_t)68247552)
#define OFF_P2    ((size_t)68255744)
#define OFF_D     ((size_t)69206016)     // 134.2 MB dmat; overlays below (stream-ordered safe)
#define OFF_T     (OFF_D + (size_t)0)           // 16 MB (alive gather_max -> bn2; dmat dead)
#define OFF_UV    (OFF_D + (size_t)50331648)    // 33.5 MB (alive uv gemm -> gather); also y
#define OFF_QW    (OFF_D + (size_t)83886080)    // 0.79 MB weight packs
#define OFF_PMAX  (OFF_D + (size_t)84672512)    // 256 KB
#define WS_NEEDED ((size_t)203423744)

// ---------------- helpers ----------------
static __device__ __forceinline__ ushort_t f2bf(float f) {
    unsigned u = __float_as_uint(f);
    unsigned r = (u + 0x7fffu + ((u >> 16) & 1u)) >> 16;   // RNE
    return (ushort_t)r;
}
static __device__ __forceinline__ float bf2f(ushort_t h) {
    return __uint_as_float(((unsigned)h) << 16);
}
// P-pack layout per row: [hi(0:256), lo(256:512), hi(512:768)]
static __device__ __forceinline__ void pack3(float v, ushort_t* A, size_t base, int f) {
    ushort_t hi = f2bf(v);
    ushort_t lo = f2bf(v - bf2f(hi));
    A[base + f] = hi; A[base + H_ + f] = lo; A[base + 2 * H_ + f] = hi;
}
static __device__ __forceinline__ unsigned sortkey(float v) {
    unsigned u = __float_as_uint(v);
    return (u & 0x80000000u) ? ~u : (u | 0x80000000u);
}

// ---------------- kernels ----------------

// h = x @ Wf + bf ; also pack h into Apack
__global__ void feat_pack(const float* __restrict__ x, const float* __restrict__ Wf,
                          const float* __restrict__ bfv, float* __restrict__ h,
                          ushort_t* __restrict__ Ap) {
    int pt = blockIdx.x;
    int f  = threadIdx.x;
    float x0 = x[pt * 3 + 0], x1 = x[pt * 3 + 1], x2 = x[pt * 3 + 2];
    float v = x0 * Wf[f] + x1 * Wf[H_ + f] + x2 * Wf[2 * H_ + f] + bfv[f];
    h[(size_t)pt * H_ + f] = v;
    pack3(v, Ap, (size_t)pt * KP_, f);
}

// W (256 x Nd) -> Qpack (Nd x 768) rows [hi,hi,lo] of W^T
__global__ void pack_wT(const float* __restrict__ W, ushort_t* __restrict__ Qp, int Nd) {
    int n = blockIdx.x, k = threadIdx.x;
    float w = W[(size_t)k * Nd + n];
    ushort_t hi = f2bf(w), lo = f2bf(w - bf2f(hi));
    size_t base = (size_t)n * KP_;
    Qp[base + k] = hi; Qp[base + H_ + k] = hi; Qp[base + 2 * H_ + k] = lo;
}

// Qcat for fused u|v gemm: rows 0..255 = (We_a - We_b)^T, rows 256..511 = We_b^T
__global__ void pack_qcat(const float* __restrict__ We_l, const float* __restrict__ be_l,
                          ushort_t* __restrict__ Qp, float* __restrict__ bcat) {
    int n = blockIdx.x, k = threadIdx.x;
    float w;
    if (n < H_) w = We_l[(size_t)k * H_ + n] - We_l[(size_t)H_ * H_ + (size_t)k * H_ + n];
    else        w = We_l[(size_t)H_ * H_ + (size_t)k * H_ + (n - H_)];
    ushort_t hi = f2bf(w), lo = f2bf(w - bf2f(hi));
    size_t base = (size_t)n * KP_;
    Qp[base + k] = hi; Qp[base + H_ + k] = hi; Qp[base + 2 * H_ + k] = lo;
    if (k == 0) bcat[n] = (n < H_) ? be_l[n] : 0.f;
}

// ---- split-bf16 MFMA GEMM: out = P (M x K) . Q^T (N x K) ----
// mode 0: out[r][c] = acc + aux[c]
// mode 2: out[r][c] = resid[r][c] + alphap[aidx]*(acc+aux[c])
// stats != nullptr: accumulate per-column sum/sumsq of written values (BN prestats)
// nx != 0: 1-D grid of nx*128 blocks, XCD-pinned: z=blk&7 owns M-rows of batch z.
__global__ __launch_bounds__(256) void mfma_gemm(
    const ushort_t* __restrict__ P, const ushort_t* __restrict__ Q,
    const float* __restrict__ aux, float* __restrict__ out,
    int Kd, int ldOut, int mode, const float* __restrict__ resid,
    const float* __restrict__ alphap, int aidx, double* __restrict__ stats,
    int nx) {
    __shared__ __align__(16) ushort_t As[128 * 32];
    __shared__ __align__(16) ushort_t Bs[128 * 32];
    __shared__ float cs1[4][64], cs2[4][64];
    int i0, j0;
    if (nx) {
        int blk = blockIdx.x;
        int z = blk & 7;
        int rest = blk >> 3;
        int xb = rest % nx;
        int ys = rest / nx;            // 0..15
        i0 = (z * 16 + ys) * 128;
        j0 = xb * 128;
    } else {
        i0 = blockIdx.y * 128; j0 = blockIdx.x * 128;
    }
    int tid = threadIdx.x;
    int lane = tid & 63, wave = tid >> 6;
    int wm = wave & 1, wn = wave >> 1;
    int m16 = lane & 15, kq = (lane >> 4) * 8;

    f32x4 acc[4][4];
    f32x4 zero = {0.f, 0.f, 0.f, 0.f};
#pragma unroll
    for (int i = 0; i < 4; ++i)
#pragma unroll
        for (int j = 0; j < 4; ++j) acc[i][j] = zero;

    int srow = tid >> 2;
    int skc  = (tid & 3) * 8;

    for (int k0 = 0; k0 < Kd; k0 += 32) {
#pragma unroll
        for (int s = 0; s < 2; ++s) {
            int row = srow + s * 64;
            const ushort_t* gpA = P + (size_t)(i0 + row) * Kd + k0 + skc;
            const ushort_t* gpB = Q + (size_t)(j0 + row) * Kd + k0 + skc;
            __builtin_amdgcn_global_load_lds(
                (const __attribute__((address_space(1))) void*)gpA,
                (__attribute__((address_space(3))) void*)(As + (size_t)(wave * 64 + s * 256) * 8),
                16, 0, 0);
            __builtin_amdgcn_global_load_lds(
                (const __attribute__((address_space(1))) void*)gpB,
                (__attribute__((address_space(3))) void*)(Bs + (size_t)(wave * 64 + s * 256) * 8),
                16, 0, 0);
        }
        __syncthreads();
        short8 af[4], bfr[4];
#pragma unroll
        for (int fi = 0; fi < 4; ++fi)
            af[fi] = *(const short8*)(As + (wm * 64 + fi * 16 + m16) * 32 + kq);
#pragma unroll
        for (int fj = 0; fj < 4; ++fj)
            bfr[fj] = *(const short8*)(Bs + (wn * 64 + fj * 16 + m16) * 32 + kq);
#pragma unroll
        for (int fi = 0; fi < 4; ++fi)
#pragma unroll
            for (int fj = 0; fj < 4; ++fj)
                acc[fi][fj] = __builtin_amdgcn_mfma_f32_16x16x32_bf16(
                    af[fi], bfr[fj], acc[fi][fj], 0, 0, 0);
        __syncthreads();
    }
    float alpha = (mode == 2) ? alphap[aidx] : 0.f;
    int rbase = i0 + wm * 64 + (lane >> 4) * 4;
    int cbase = j0 + wn * 64 + m16;
    float s1[4] = {0.f, 0.f, 0.f, 0.f}, s2[4] = {0.f, 0.f, 0.f, 0.f};
#pragma unroll
    for (int fi = 0; fi < 4; ++fi) {
#pragma unroll
        for (int fj = 0; fj < 4; ++fj) {
            int c = cbase + fj * 16;
            float a = aux[c];
#pragma unroll
            for (int r = 0; r < 4; ++r) {
                int gr = rbase + fi * 16 + r;
                size_t oidx = (size_t)gr * ldOut + c;
                float val;
                if (mode == 2) val = resid[oidx] + alpha * (acc[fi][fj][r] + a);
                else           val = acc[fi][fj][r] + a;
                out[oidx] = val;
                s1[fj] += val; s2[fj] += val * val;
            }
        }
    }
    if (stats) {
#pragma unroll
        for (int fj = 0; fj < 4; ++fj) {
            float a1 = s1[fj], a2 = s2[fj];
            a1 += __shfl_xor(a1, 16); a1 += __shfl_xor(a1, 32);
            a2 += __shfl_xor(a2, 16); a2 += __shfl_xor(a2, 32);
            if ((lane >> 4) == 0) {
                cs1[wave][fj * 16 + m16] = a1;
                cs2[wave][fj * 16 + m16] = a2;
            }
        }
        __syncthreads();
        if (tid < 128) {
            int wnl = tid >> 6, cl = tid & 63;
            float t1 = cs1[2 * wnl][cl] + cs1[2 * wnl + 1][cl];
            float t2 = cs2[2 * wnl][cl] + cs2[2 * wnl + 1][cl];
            int c = j0 + tid;
            atomicAdd(&stats[c], (double)t1);
            atomicAdd(&stats[H_ + c], (double)t2);
        }
    }
}

// ---- symmetric gram: D[i][j] = sq[j] - 2 <x_i, x_j>, upper-tri tile pairs only ----
// 1-D grid 1088: z = blk&7 (XCD pin), p = blk>>3 enumerates bi<=bj tile pairs.
// B-side reads P-pack with segment remap (0,2,1).
// Epilogue: wave-private LDS transpose -> f32x4 NT stores; also emits per-row
// 32-col-chunk minima (cmin, BN x 64) for the hierarchical top-k filter.
__global__ __launch_bounds__(256) void gram_sym(const ushort_t* __restrict__ Ap,
                                                const float* __restrict__ sqb,
                                                float* __restrict__ D,
                                                float* __restrict__ cminb) {
    __shared__ __align__(16) ushort_t As[128 * 32];
    __shared__ __align__(16) ushort_t Bs[128 * 32];
    __shared__ __align__(16) float stg[4][1280];   // wave-private transpose pool
    int blk = blockIdx.x;
    int z = blk & 7;
    int p = blk >> 3;
    int bi = 0, rem = p;
    while (rem >= 16 - bi) { rem -= 16 - bi; ++bi; }
    int bj = bi + rem;
    const ushort_t* Pz = Ap + (size_t)z * N_ * KP_;
    const float* sqz = sqb + (size_t)z * N_;
    float* Dz = D + (size_t)z * N_ * N_;
    float* cz = cminb + (size_t)z * N_ * 64;
    int i0 = bi * 128, j0 = bj * 128;

    int tid = threadIdx.x;
    int lane = tid & 63, wave = tid >> 6;
    int wm = wave & 1, wn = wave >> 1;
    int m16 = lane & 15, q4 = lane >> 4;
    int kq = q4 * 8;

    f32x4 acc[4][4];
    f32x4 zero = {0.f, 0.f, 0.f, 0.f};
#pragma unroll
    for (int i = 0; i < 4; ++i)
#pragma unroll
        for (int j = 0; j < 4; ++j) acc[i][j] = zero;

    int srow = tid >> 2;
    int skc  = (tid & 3) * 8;

    for (int k0 = 0; k0 < KP_; k0 += 32) {
        // Q segment remap: seg0->seg0(hi), seg1->seg2(hi), seg2->seg1(lo)
        int kb = (k0 < 256) ? k0 : ((k0 < 512) ? k0 + 256 : k0 - 256);
#pragma unroll
        for (int s = 0; s < 2; ++s) {
            int row = srow + s * 64;
            const ushort_t* gpA = Pz + (size_t)(i0 + row) * KP_ + k0 + skc;
            const ushort_t* gpB = Pz + (size_t)(j0 + row) * KP_ + kb + skc;
            __builtin_amdgcn_global_load_lds(
                (const __attribute__((address_space(1))) void*)gpA,
                (__attribute__((address_space(3))) void*)(As + (size_t)(wave * 64 + s * 256) * 8),
                16, 0, 0);
            __builtin_amdgcn_global_load_lds(
                (const __attribute__((address_space(1))) void*)gpB,
                (__attribute__((address_space(3))) void*)(Bs + (size_t)(wave * 64 + s * 256) * 8),
                16, 0, 0);
        }
        __syncthreads();
        short8 af[4], bfr[4];
#pragma unroll
        for (int fi = 0; fi < 4; ++fi)
            af[fi] = *(const short8*)(As + (wm * 64 + fi * 16 + m16) * 32 + kq);
#pragma unroll
        for (int fj = 0; fj < 4; ++fj)
            bfr[fj] = *(const short8*)(Bs + (wn * 64 + fj * 16 + m16) * 32 + kq);
#pragma unroll
        for (int fi = 0; fi < 4; ++fi)
#pragma unroll
            for (int fj = 0; fj < 4; ++fj)
                acc[fi][fj] = __builtin_amdgcn_mfma_f32_16x16x32_bf16(
                    af[fi], bfr[fj], acc[fi][fj], 0, 0, 0);
        __syncthreads();
    }

    float* sg = stg[wave];
    float scl[4];
#pragma unroll
    for (int fj = 0; fj < 4; ++fj) scl[fj] = sqz[j0 + wn * 64 + fj * 16 + m16];
    float sr[4][4];
#pragma unroll
    for (int fi = 0; fi < 4; ++fi) {
        float4 s4 = *(const float4*)(sqz + i0 + wm * 64 + fi * 16 + q4 * 4);
        sr[fi][0] = s4.x; sr[fi][1] = s4.y; sr[fi][2] = s4.z; sr[fi][3] = s4.w;
    }

    // ---- chunk-min emission (normal orientation rows) ----
#pragma unroll
    for (int fi = 0; fi < 4; ++fi) {
#pragma unroll
        for (int r = 0; r < 4; ++r) {
            float m0 = fminf(scl[0] - 2.f * acc[fi][0][r], scl[1] - 2.f * acc[fi][1][r]);
            float m1 = fminf(scl[2] - 2.f * acc[fi][2][r], scl[3] - 2.f * acc[fi][3][r]);
#pragma unroll
            for (int off = 1; off < 16; off <<= 1) {
                m0 = fminf(m0, __shfl_xor(m0, off));
                m1 = fminf(m1, __shfl_xor(m1, off));
            }
            if (m16 == 0) {
                int row = i0 + wm * 64 + fi * 16 + q4 * 4 + r;
                cz[(size_t)row * 64 + bj * 4 + wn * 2 + 0] = m0;
                cz[(size_t)row * 64 + bj * 4 + wn * 2 + 1] = m1;
            }
        }
    }
    // ---- chunk-min emission (transposed orientation rows, off-diag only) ----
    if (bi != bj) {
#pragma unroll
        for (int fj = 0; fj < 4; ++fj) {
            float mp0 = FLT_MAX, mp1 = FLT_MAX;
#pragma unroll
            for (int r = 0; r < 4; ++r) {
                mp0 = fminf(mp0, fminf(sr[0][r] - 2.f * acc[0][fj][r],
                                       sr[1][r] - 2.f * acc[1][fj][r]));
                mp1 = fminf(mp1, fminf(sr[2][r] - 2.f * acc[2][fj][r],
                                       sr[3][r] - 2.f * acc[3][fj][r]));
            }
            mp0 = fminf(mp0, __shfl_xor(mp0, 16)); mp0 = fminf(mp0, __shfl_xor(mp0, 32));
            mp1 = fminf(mp1, __shfl_xor(mp1, 16)); mp1 = fminf(mp1, __shfl_xor(mp1, 32));
            if (q4 == 0) {
                int row = j0 + wn * 64 + fj * 16 + m16;
                cz[(size_t)row * 64 + bi * 4 + wm * 2 + 0] = mp0;
                cz[(size_t)row * 64 + bi * 4 + wm * 2 + 1] = mp1;
            }
        }
    }

    // normal orientation: per fi, wave-private [16][68] transpose -> f32x4 stores
    int rr = lane >> 2, cc = lane & 3;
#pragma unroll
    for (int fi = 0; fi < 4; ++fi) {
#pragma unroll
        for (int fj = 0; fj < 4; ++fj)
#pragma unroll
            for (int r = 0; r < 4; ++r)
                sg[(q4 * 4 + r) * 68 + fj * 16 + m16] = scl[fj] - 2.f * acc[fi][fj][r];
        float* drow = Dz + (size_t)(i0 + wm * 64 + fi * 16 + rr) * N_ + j0 + wn * 64;
#pragma unroll
        for (int t = 0; t < 4; ++t) {
            int chunk = cc + 4 * t;
            f32x4 o = *(const f32x4*)(sg + rr * 68 + chunk * 4);
            __builtin_nontemporal_store(o, (f32x4*)(drow + chunk * 4));
        }
    }

    // transposed orientation (off-diag): per fi, wave-private [64][20] -> f32x4 stores
    if (bi != bj) {
#pragma unroll
        for (int fi = 0; fi < 4; ++fi) {
#pragma unroll
            for (int fj = 0; fj < 4; ++fj)
#pragma unroll
                for (int r = 0; r < 4; ++r)
                    sg[(fj * 16 + m16) * 20 + q4 * 4 + r] =
                        sr[fi][r] - 2.f * acc[fi][fj][r];
            int chunk = lane & 3;
#pragma unroll
            for (int u = 0; u < 4; ++u) {
                int cr = (lane >> 2) + 16 * u;
                f32x4 o = *(const f32x4*)(sg + cr * 20 + chunk * 4);
                __builtin_nontemporal_store(o,
                    (f32x4*)(Dz + (size_t)(j0 + wn * 64 + cr) * N_ +
                             i0 + wm * 64 + fi * 16 + chunk * 4));
            }
        }
    }
}

// ---- hierarchical top-16 (exact): chunk-min threshold -> sparse D scan ----
// T = 16th smallest of 64 chunk-mins bounds the row's 16th order statistic;
// only chunks with min <= T are scanned (expected ~16 of 64).
__global__ __launch_bounds__(256) void topk16(const float* __restrict__ D,
                                              const float* __restrict__ cminb,
                                              int* __restrict__ idxb) {
    __shared__ unsigned long long cand[4][256];
    __shared__ int cnt[4];
    int w = threadIdx.x >> 6, lane = threadIdx.x & 63;
    int row = blockIdx.x * 4 + w;
    const float* dp = D + (size_t)row * N_;
    float cm = cminb[(size_t)row * 64 + lane];
    unsigned mykey = sortkey(cm);
    if (lane == 0) cnt[w] = 0;
    // bitonic sort of 64 chunk-min keys (ascending across lanes)
    unsigned vm = mykey;
#pragma unroll
    for (int k = 2; k <= 64; k <<= 1) {
#pragma unroll
        for (int j = k >> 1; j > 0; j >>= 1) {
            unsigned pv = __shfl_xor(vm, j);
            bool up = ((lane & k) == 0);
            bool lower = ((lane & j) == 0);
            unsigned mn = min(vm, pv), mx = max(vm, pv);
            vm = (lower == up) ? mn : mx;
        }
    }
    unsigned T = __shfl(vm, 15);
    unsigned long long act = __ballot(mykey <= T);
    __syncthreads();
    // scan active chunks, 2 per iteration (half-wave each, 32 cols coalesced)
    int half = lane >> 5, sub = lane & 31;
    unsigned long long a = act;
    while (a) {
        int c0 = __ffsll((long long)a) - 1; a &= a - 1;
        int c1 = -1;
        if (a) { c1 = __ffsll((long long)a) - 1; a &= a - 1; }
        int c = half ? c1 : c0;
        if (c >= 0) {
            int col = c * 32 + sub;
            float v = __builtin_nontemporal_load(dp + col);
            unsigned sk2 = sortkey(v);
            if (sk2 <= T) {
                int s = atomicAdd(&cnt[w], 1);
                if (s < 256)
                    cand[w][s] = ((unsigned long long)sk2 << 32) | (unsigned)col;
            }
        }
    }
    __syncthreads();
    int cn = cnt[w];
    if (cn <= 64) {
        unsigned long long mk = (lane < cn) ? cand[w][lane] : ~0ull;
        for (int it = 0; it < 16; ++it) {
            unsigned long long best = mk;
#pragma unroll
            for (int off = 32; off; off >>= 1) {
                unsigned long long o = __shfl_xor(best, off);
                if (o < best) best = o;
            }
            if (mk == best) mk = ~0ull;
            if (lane == 0) idxb[row * 16 + it] = (int)(unsigned)(best & 0xffffffffu);
        }
    } else if (cn <= 256) {
        for (int it = 0; it < 16; ++it) {
            unsigned long long best = ~0ull;
            for (int i = lane; i < cn; i += 64) {
                unsigned long long c = cand[w][i];
                if (c < best) best = c;
            }
#pragma unroll
            for (int off = 32; off; off >>= 1) {
                unsigned long long o = __shfl_xor(best, off);
                if (o < best) best = o;
            }
            for (int i = lane; i < cn; i += 64)
                if (cand[w][i] == best) cand[w][i] = ~0ull;
            if (lane == 0) idxb[row * 16 + it] = (int)(unsigned)(best & 0xffffffffu);
        }
    } else {
        // pathological tie storm: exact full-scan iterative selection
        unsigned sk[32];
#pragma unroll
        for (int t = 0; t < 8; ++t) {
            f32x4 v4 = __builtin_nontemporal_load((const f32x4*)(dp + t * 256 + lane * 4));
#pragma unroll
            for (int j = 0; j < 4; ++j) sk[t * 4 + j] = sortkey(v4[j]);
        }
        unsigned mask = 0;
        for (int it = 0; it < 16; ++it) {
            unsigned long long key = ~0ull;
#pragma unroll
            for (int i = 0; i < 32; ++i) {
                if (!((mask >> i) & 1u)) {
                    unsigned long long k2 = ((unsigned long long)sk[i] << 32) |
                        (unsigned)((i >> 2) * 256 + lane * 4 + (i & 3));
                    if (k2 < key) key = k2;
                }
            }
#pragma unroll
            for (int off = 32; off; off >>= 1) {
                unsigned long long o = __shfl_xor(key, off);
                if (o < key) key = o;
            }
            unsigned jc = (unsigned)(key & 0xffffffffu);
            int li = ((jc & 255) >> 2);
            int ii = ((jc >> 8) << 2) | (jc & 3);
            if (lane == li) mask |= 1u << ii;
            if (lane == 0) idxb[row * 16 + it] = (int)jc;
        }
    }
}

// t[b,i,h] = uv[row][h] + max_k uv[(b,idx_k)][256+h]; accumulates BN stats of t.
// XCD-pinned: z = blk&7 -> each XCD gathers within its own batch's 2 MB v-half.
__global__ void gather_max(const float* __restrict__ uv, const int* __restrict__ idxb,
                           float* __restrict__ outp, double* __restrict__ stats) {
    int blk = blockIdx.x;
    int b = blk & 7;
    int strip = blk >> 3;               // 0..63
    int r0 = b * N_ + strip * 32;
    int f = threadIdx.x;
    float s1 = 0.f, s2 = 0.f;
    for (int rr = 0; rr < 32; ++rr) {
        int row = r0 + rr;
        const int* ip = idxb + row * 16;
        float m = -FLT_MAX;
#pragma unroll
        for (int k = 0; k < 16; ++k) {
            int j = ip[k];
            m = fmaxf(m, uv[((size_t)((b << 11) + j)) * 512 + 256 + f]);
        }
        float v = uv[(size_t)row * 512 + f] + m;
        outp[(size_t)row * H_ + f] = v;
        s1 += v; s2 += v * v;
    }
    atomicAdd(&stats[f], (double)s1);
    atomicAdd(&stats[H_ + f], (double)s2);
}

// ---- batchnorm helpers ----
__global__ void bn_zero(double* s) { s[threadIdx.x] = 0.0; }

// reads per-feature sums, emits scale/shift, re-zeroes sums for the next user
__global__ void bn_final(double* __restrict__ sums, const float* __restrict__ g,
                         const float* __restrict__ b, float* __restrict__ scsh) {
    int f = threadIdx.x;
    double m  = sums[f] / (double)BN_;
    double var = sums[H_ + f] / (double)BN_ - m * m;
    double inv = 1.0 / sqrt(var + 1e-5);
    float sc = g[f] * (float)inv;
    scsh[f] = sc;
    scsh[H_ + f] = b[f] - (float)m * sc;
    sums[f] = 0.0; sums[H_ + f] = 0.0;
}

// BN+ReLU fused with split-bf16 packing and (optional) row sqnorm reduce.
// Vectorized: one wave = 2 rows, lane owns 8 contiguous features.
__global__ void bn_apply_pack(const float* __restrict__ X, const float* __restrict__ scsh,
                              ushort_t* __restrict__ Ap, float* __restrict__ sq) {
    int tid = threadIdx.x;
    int row = blockIdx.x * 8 + (tid >> 5);
    int f0  = (tid & 31) * 8;
    const float* xp = X + (size_t)row * H_ + f0;
    f32x4 x0 = *(const f32x4*)(xp);
    f32x4 x1 = *(const f32x4*)(xp + 4);
    f32x4 sc0 = *(const f32x4*)(scsh + f0);
    f32x4 sc1 = *(const f32x4*)(scsh + f0 + 4);
    f32x4 sh0 = *(const f32x4*)(scsh + H_ + f0);
    f32x4 sh1 = *(const f32x4*)(scsh + H_ + f0 + 4);
    float v[8];
#pragma unroll
    for (int i = 0; i < 4; ++i) {
        v[i]     = fmaxf(x0[i] * sc0[i] + sh0[i], 0.f);
        v[i + 4] = fmaxf(x1[i] * sc1[i] + sh1[i], 0.f);
    }
    short8 hi8, lo8;
#pragma unroll
    for (int i = 0; i < 8; ++i) {
        ushort_t hi = f2bf(v[i]);
        ushort_t lo = f2bf(v[i] - bf2f(hi));
        hi8[i] = (short)hi; lo8[i] = (short)lo;
    }
    ushort_t* ap = Ap + (size_t)row * KP_ + f0;
    *(short8*)(ap)            = hi8;
    *(short8*)(ap + H_)       = lo8;
    *(short8*)(ap + 2 * H_)   = hi8;
    if (sq) {
        float s = 0.f;
#pragma unroll
        for (int i = 0; i < 8; ++i) s += v[i] * v[i];
#pragma unroll
        for (int off = 16; off; off >>= 1) s += __shfl_down(s, off, 32);
        if ((tid & 31) == 0) sq[row] = s;
    }
}

__global__ void maxpool1(const float* __restrict__ y, float* __restrict__ pmax) {
    int b = blockIdx.x, gc = blockIdx.y, nc = blockIdx.z;
    int g = gc * 256 + threadIdx.x;
    const float* yb = y + ((size_t)b * N_ + (size_t)nc * 128) * G_;
    float m = -FLT_MAX;
    for (int n = 0; n < 128; ++n) m = fmaxf(m, yb[(size_t)n * G_ + g]);
    pmax[((size_t)(b * 16 + nc)) * G_ + g] = m;
}

__global__ void maxpool2(const float* __restrict__ pmax, float* __restrict__ p) {
    int b = blockIdx.x;
    int g = blockIdx.y * 256 + threadIdx.x;
    float m = -FLT_MAX;
    for (int c = 0; c < 16; ++c) m = fmaxf(m, pmax[((size_t)(b * 16 + c)) * G_ + g]);
    p[(size_t)b * G_ + g] = m;
}

// parallel split-K head gemm: grid(M, Nd/64), 256 thr = 64 cols x 4 k-slices
__global__ __launch_bounds__(256) void head_gemm(const float* __restrict__ A,
                                                 const float* __restrict__ W,
                                                 const float* __restrict__ bias,
                                                 float* __restrict__ Cc,
                                                 int Kd, int Nd, int relu) {
    int m = blockIdx.x;
    int c0 = blockIdx.y * 64;
    int cl = threadIdx.x & 63;
    int ks = threadIdx.x >> 6;
    int kper = Kd >> 2;
    const float* Ap = A + (size_t)m * Kd + (size_t)ks * kper;
    const float* Wp = W + (size_t)ks * kper * Nd + c0 + cl;
    float acc = 0.f;
    for (int k = 0; k < kper; k += 8) {
#pragma unroll
        for (int u2 = 0; u2 < 8; ++u2)
            acc += Ap[k + u2] * Wp[(size_t)(k + u2) * Nd];
    }
    __shared__ float red[4][64];
    red[ks][cl] = acc;
    __syncthreads();
    if (ks == 0) {
        float s = red[0][cl] + red[1][cl] + red[2][cl] + red[3][cl] + bias[c0 + cl];
        if (relu) s = fmaxf(s, 0.f);
        Cc[(size_t)m * Nd + c0 + cl] = s;
    }
}

// ---------------- launch ----------------
extern "C" void kernel_launch(void* const* d_in, const int* in_sizes, int n_in,
                              void* d_out, int out_size, void* d_ws, size_t ws_size,
                              hipStream_t stream) {
    (void)in_sizes; (void)n_in; (void)out_size;
    if (ws_size < WS_NEEDED) return;

    const float* x    = (const float*)d_in[0];
    const float* Wf   = (const float*)d_in[2];
    const float* bfv  = (const float*)d_in[3];
    const float* Wnn  = (const float*)d_in[4];
    const float* bnn  = (const float*)d_in[5];
    const float* g1   = (const float*)d_in[6];
    const float* b1   = (const float*)d_in[7];
    const float* We   = (const float*)d_in[8];
    const float* be   = (const float*)d_in[9];
    const float* g2   = (const float*)d_in[10];
    const float* b2   = (const float*)d_in[11];
    const float* Wl   = (const float*)d_in[12];
    const float* bl   = (const float*)d_in[13];
    const float* alpha= (const float*)d_in[14];
    const float* gg   = (const float*)d_in[15];
    const float* bgb  = (const float*)d_in[16];
    const float* Wg   = (const float*)d_in[17];
    const float* bg2  = (const float*)d_in[18];
    const float* Wm1  = (const float*)d_in[19];
    const float* bm1  = (const float*)d_in[20];
    const float* Wm2  = (const float*)d_in[21];
    const float* bm2  = (const float*)d_in[22];
    const float* Wm3  = (const float*)d_in[23];
    const float* bm3  = (const float*)d_in[24];
    float* outp = (float*)d_out;

    char* ws = (char*)d_ws;
    float*    h    = (float*)(ws + OFF_H);
    ushort_t* Ap   = (ushort_t*)(ws + OFF_APACK);
    float*    cmin = (float*)(ws + OFF_CMIN);
    float*    sqb  = (float*)(ws + OFF_SQ);
    int*      idxb = (int*)  (ws + OFF_IDX);
    double*   stats= (double*)(ws + OFF_STATS);
    float*    scsh = (float*)(ws + OFF_SCSH);
    float*    bcat = (float*)(ws + OFF_BCAT);
    float*    p0   = (float*)(ws + OFF_P0);
    float*    p1   = (float*)(ws + OFF_P1);
    float*    p2   = (float*)(ws + OFF_P2);
    float*    dmat = (float*)(ws + OFF_D);
    float*    t    = (float*)(ws + OFF_T);
    float*    uv   = (float*)(ws + OFF_UV);
    float*    y    = (float*)(ws + OFF_UV);
    ushort_t* Qw   = (ushort_t*)(ws + OFF_QW);
    float*    pmax = (float*)(ws + OFF_PMAX);

    // one-time zero (ws is re-poisoned before every call); bn_final re-zeroes after use
    hipLaunchKernelGGL(bn_zero, dim3(1), dim3(512), 0, stream, stats);

    // h = x@Wf+bf (+pack), t = h@Wnn+bnn via MFMA (accumulates t-stats), XCD-pinned
    hipLaunchKernelGGL(feat_pack, dim3(BN_), dim3(256), 0, stream, x, Wf, bfv, h, Ap);
    hipLaunchKernelGGL(pack_wT, dim3(H_), dim3(256), 0, stream, Wnn, Qw, H_);
    hipLaunchKernelGGL(mfma_gemm, dim3(256), dim3(256), 0, stream,
                       Ap, Qw, bnn, t, KP_, H_, 0,
                       (const float*)nullptr, (const float*)nullptr, 0, stats, 2);

    for (int l = 0; l < L_; ++l) {
        const float* src1 = (l == 0) ? t : h;
        hipLaunchKernelGGL(bn_final, dim3(1), dim3(256), 0, stream,
                           stats, g1 + l * H_, b1 + l * H_, scsh);
        hipLaunchKernelGGL(bn_apply_pack, dim3(BN_ / 8), dim3(256), 0, stream,
                           src1, scsh, Ap, sqb);
        // symmetric gram -> D + chunk-min matrix, XCD-pinned
        hipLaunchKernelGGL(gram_sym, dim3(1088), dim3(256), 0, stream,
                           Ap, sqb, dmat, cmin);
        hipLaunchKernelGGL(topk16, dim3(BN_ / 4), dim3(256), 0, stream,
                           dmat, cmin, idxb);
        // fused u|v gemm (N=512), XCD-pinned
        hipLaunchKernelGGL(pack_qcat, dim3(512), dim3(256), 0, stream,
                           We + (size_t)l * 2 * H_ * H_, be + (size_t)l * H_, Qw, bcat);
        hipLaunchKernelGGL(mfma_gemm, dim3(512), dim3(256), 0, stream,
                           Ap, Qw, bcat, uv, KP_, 512, 0,
                           (const float*)nullptr, (const float*)nullptr, 0,
                           (double*)nullptr, 4);
        hipLaunchKernelGGL(gather_max, dim3(512), dim3(256), 0, stream,
                           uv, idxb, t, stats);
        // BN2 + Wl with fused residual: h = h + alpha[l]*(xb@Wl + bl) (+h-stats)
        hipLaunchKernelGGL(bn_final, dim3(1), dim3(256), 0, stream,
                           stats, g2 + l * H_, b2 + l * H_, scsh);
        hipLaunchKernelGGL(bn_apply_pack, dim3(BN_ / 8), dim3(256), 0, stream,
                           t, scsh, Ap, (float*)nullptr);
        hipLaunchKernelGGL(pack_wT, dim3(H_), dim3(256), 0, stream,
                           Wl + (size_t)l * H_ * H_, Qw, H_);
        hipLaunchKernelGGL(mfma_gemm, dim3(256), dim3(256), 0, stream,
                           Ap, Qw, bl + (size_t)l * H_, h, KP_, H_, 2,
                           h, alpha, l, stats, 2);
    }

    // head
    hipLaunchKernelGGL(bn_final, dim3(1), dim3(256), 0, stream, stats, gg, bgb, scsh);
    hipLaunchKernelGGL(bn_apply_pack, dim3(BN_ / 8), dim3(256), 0, stream,
                       h, scsh, Ap, (float*)nullptr);
    hipLaunchKernelGGL(pack_wT, dim3(G_), dim3(256), 0, stream, Wg, Qw, G_);
    hipLaunchKernelGGL(mfma_gemm, dim3(512), dim3(256), 0, stream,
                       Ap, Qw, bg2, y, KP_, G_, 0,
                       (const float*)nullptr, (const float*)nullptr, 0,
                       (double*)nullptr, 4);
    hipLaunchKernelGGL(maxpool1, dim3(8, 2, 16), dim3(256), 0, stream, y, pmax);
    hipLaunchKernelGGL(maxpool2, dim3(8, 2), dim3(256), 0, stream, pmax, p0);
    hipLaunchKernelGGL(head_gemm, dim3(8, 4), dim3(256), 0, stream, p0, Wm1, bm1, p1, G_, M0_, 1);
    hipLaunchKernelGGL(head_gemm, dim3(8, 2), dim3(256), 0, stream, p1, Wm2, bm2, p2, M0_, M1_, 1);
    hipLaunchKernelGGL(head_gemm, dim3(8, 2), dim3(256), 0, stream, p2, Wm3, bm3, outp, M1_, C_, 0);
}

// Round 15
// 1129.169 us; speedup vs baseline: 1.1208x; 1.1208x over previous
//
#include <hip/hip_runtime.h>
#include <cfloat>

#define B_  8
#define N_  2048
#define H_  256
#define L_  4
#define K_  16
#define G_  512
#define M0_ 256
#define M1_ 128
#define C_  128
#define BN_ 16384   // B_*N_
#define KP_ 768     // packed split-bf16 K (3*H_)

typedef unsigned short ushort_t;
typedef __attribute__((ext_vector_type(8))) short short8;
typedef __attribute__((ext_vector_type(4))) float f32x4;

// ---------------- workspace layout (bytes) ----------------
#define OFF_H     ((size_t)0)            // 16 MB  h (fp32, persistent)
#define OFF_APACK ((size_t)16777216)     // 25.2 MB  P-pack [hi,lo,hi] (Q read via seg remap)
#define OFF_SQ    ((size_t)67108864)     // 64 KB
#define OFF_IDX   ((size_t)67174400)     // 1 MB
#define OFF_STATS ((size_t)68222976)     // 4 KB (512 doubles)
#define OFF_SCSH  ((size_t)68227072)     // 2 KB
#define OFF_BCAT  ((size_t)68229120)     // 2 KB
#define OFF_P0    ((size_t)68231168)     // 16 KB
#define OFF_P1    ((size_t)68247552)
#define OFF_P2    ((size_t)68255744)
#define OFF_D     ((size_t)69206016)     // 134.2 MB dmat; overlays below (stream-ordered safe)
#define OFF_T     (OFF_D + (size_t)0)           // 16 MB (alive gather_max -> bn2; dmat dead)
#define OFF_UV    (OFF_D + (size_t)50331648)    // 33.5 MB (alive uv gemm -> gather); also y
#define OFF_QW    (OFF_D + (size_t)83886080)    // 0.79 MB weight packs
#define OFF_PMAX  (OFF_D + (size_t)84672512)    // 256 KB
#define WS_NEEDED ((size_t)203423744)

// ---------------- helpers ----------------
static __device__ __forceinline__ ushort_t f2bf(float f) {
    unsigned u = __float_as_uint(f);
    unsigned r = (u + 0x7fffu + ((u >> 16) & 1u)) >> 16;   // RNE
    return (ushort_t)r;
}
static __device__ __forceinline__ float bf2f(ushort_t h) {
    return __uint_as_float(((unsigned)h) << 16);
}
// P-pack layout per row: [hi(0:256), lo(256:512), hi(512:768)]
static __device__ __forceinline__ void pack3(float v, ushort_t* A, size_t base, int f) {
    ushort_t hi = f2bf(v);
    ushort_t lo = f2bf(v - bf2f(hi));
    A[base + f] = hi; A[base + H_ + f] = lo; A[base + 2 * H_ + f] = hi;
}

// ---------------- kernels ----------------

// h = x @ Wf + bf ; also pack h into Apack
__global__ void feat_pack(const float* __restrict__ x, const float* __restrict__ Wf,
                          const float* __restrict__ bfv, float* __restrict__ h,
                          ushort_t* __restrict__ Ap) {
    int pt = blockIdx.x;
    int f  = threadIdx.x;
    float x0 = x[pt * 3 + 0], x1 = x[pt * 3 + 1], x2 = x[pt * 3 + 2];
    float v = x0 * Wf[f] + x1 * Wf[H_ + f] + x2 * Wf[2 * H_ + f] + bfv[f];
    h[(size_t)pt * H_ + f] = v;
    pack3(v, Ap, (size_t)pt * KP_, f);
}

// W (256 x Nd) -> Qpack (Nd x 768) rows [hi,hi,lo] of W^T
__global__ void pack_wT(const float* __restrict__ W, ushort_t* __restrict__ Qp, int Nd) {
    int n = blockIdx.x, k = threadIdx.x;
    float w = W[(size_t)k * Nd + n];
    ushort_t hi = f2bf(w), lo = f2bf(w - bf2f(hi));
    size_t base = (size_t)n * KP_;
    Qp[base + k] = hi; Qp[base + H_ + k] = hi; Qp[base + 2 * H_ + k] = lo;
}

// Qcat for fused u|v gemm: rows 0..255 = (We_a - We_b)^T, rows 256..511 = We_b^T
__global__ void pack_qcat(const float* __restrict__ We_l, const float* __restrict__ be_l,
                          ushort_t* __restrict__ Qp, float* __restrict__ bcat) {
    int n = blockIdx.x, k = threadIdx.x;
    float w;
    if (n < H_) w = We_l[(size_t)k * H_ + n] - We_l[(size_t)H_ * H_ + (size_t)k * H_ + n];
    else        w = We_l[(size_t)H_ * H_ + (size_t)k * H_ + (n - H_)];
    ushort_t hi = f2bf(w), lo = f2bf(w - bf2f(hi));
    size_t base = (size_t)n * KP_;
    Qp[base + k] = hi; Qp[base + H_ + k] = hi; Qp[base + 2 * H_ + k] = lo;
    if (k == 0) bcat[n] = (n < H_) ? be_l[n] : 0.f;
}

// ---- split-bf16 MFMA GEMM: out = P (M x K) . Q^T (N x K) ----
// mode 0: out[r][c] = acc + aux[c]
// mode 2: out[r][c] = resid[r][c] + alphap[aidx]*(acc+aux[c])
// stats != nullptr: accumulate per-column sum/sumsq of written values (BN prestats)
// nx != 0: 1-D grid of nx*128 blocks, XCD-pinned: z=blk&7 owns M-rows of batch z.
__global__ __launch_bounds__(256) void mfma_gemm(
    const ushort_t* __restrict__ P, const ushort_t* __restrict__ Q,
    const float* __restrict__ aux, float* __restrict__ out,
    int Kd, int ldOut, int mode, const float* __restrict__ resid,
    const float* __restrict__ alphap, int aidx, double* __restrict__ stats,
    int nx) {
    __shared__ __align__(16) ushort_t As[128 * 32];
    __shared__ __align__(16) ushort_t Bs[128 * 32];
    __shared__ float cs1[4][64], cs2[4][64];
    int i0, j0;
    if (nx) {
        int blk = blockIdx.x;
        int z = blk & 7;
        int rest = blk >> 3;
        int xb = rest % nx;
        int ys = rest / nx;            // 0..15
        i0 = (z * 16 + ys) * 128;
        j0 = xb * 128;
    } else {
        i0 = blockIdx.y * 128; j0 = blockIdx.x * 128;
    }
    int tid = threadIdx.x;
    int lane = tid & 63, wave = tid >> 6;
    int wm = wave & 1, wn = wave >> 1;
    int m16 = lane & 15, kq = (lane >> 4) * 8;

    f32x4 acc[4][4];
    f32x4 zero = {0.f, 0.f, 0.f, 0.f};
#pragma unroll
    for (int i = 0; i < 4; ++i)
#pragma unroll
        for (int j = 0; j < 4; ++j) acc[i][j] = zero;

    int srow = tid >> 2;
    int skc  = (tid & 3) * 8;

    for (int k0 = 0; k0 < Kd; k0 += 32) {
#pragma unroll
        for (int s = 0; s < 2; ++s) {
            int row = srow + s * 64;
            const ushort_t* gpA = P + (size_t)(i0 + row) * Kd + k0 + skc;
            const ushort_t* gpB = Q + (size_t)(j0 + row) * Kd + k0 + skc;
            __builtin_amdgcn_global_load_lds(
                (const __attribute__((address_space(1))) void*)gpA,
                (__attribute__((address_space(3))) void*)(As + (size_t)(wave * 64 + s * 256) * 8),
                16, 0, 0);
            __builtin_amdgcn_global_load_lds(
                (const __attribute__((address_space(1))) void*)gpB,
                (__attribute__((address_space(3))) void*)(Bs + (size_t)(wave * 64 + s * 256) * 8),
                16, 0, 0);
        }
        __syncthreads();
        short8 af[4], bfr[4];
#pragma unroll
        for (int fi = 0; fi < 4; ++fi)
            af[fi] = *(const short8*)(As + (wm * 64 + fi * 16 + m16) * 32 + kq);
#pragma unroll
        for (int fj = 0; fj < 4; ++fj)
            bfr[fj] = *(const short8*)(Bs + (wn * 64 + fj * 16 + m16) * 32 + kq);
#pragma unroll
        for (int fi = 0; fi < 4; ++fi)
#pragma unroll
            for (int fj = 0; fj < 4; ++fj)
                acc[fi][fj] = __builtin_amdgcn_mfma_f32_16x16x32_bf16(
                    af[fi], bfr[fj], acc[fi][fj], 0, 0, 0);
        __syncthreads();
    }
    float alpha = (mode == 2) ? alphap[aidx] : 0.f;
    int rbase = i0 + wm * 64 + (lane >> 4) * 4;
    int cbase = j0 + wn * 64 + m16;
    float s1[4] = {0.f, 0.f, 0.f, 0.f}, s2[4] = {0.f, 0.f, 0.f, 0.f};
#pragma unroll
    for (int fi = 0; fi < 4; ++fi) {
#pragma unroll
        for (int fj = 0; fj < 4; ++fj) {
            int c = cbase + fj * 16;
            float a = aux[c];
#pragma unroll
            for (int r = 0; r < 4; ++r) {
                int gr = rbase + fi * 16 + r;
                size_t oidx = (size_t)gr * ldOut + c;
                float val;
                if (mode == 2) val = resid[oidx] + alpha * (acc[fi][fj][r] + a);
                else           val = acc[fi][fj][r] + a;
                out[oidx] = val;
                s1[fj] += val; s2[fj] += val * val;
            }
        }
    }
    if (stats) {
#pragma unroll
        for (int fj = 0; fj < 4; ++fj) {
            float a1 = s1[fj], a2 = s2[fj];
            a1 += __shfl_xor(a1, 16); a1 += __shfl_xor(a1, 32);
            a2 += __shfl_xor(a2, 16); a2 += __shfl_xor(a2, 32);
            if ((lane >> 4) == 0) {
                cs1[wave][fj * 16 + m16] = a1;
                cs2[wave][fj * 16 + m16] = a2;
            }
        }
        __syncthreads();
        if (tid < 128) {
            int wnl = tid >> 6, cl = tid & 63;
            float t1 = cs1[2 * wnl][cl] + cs1[2 * wnl + 1][cl];
            float t2 = cs2[2 * wnl][cl] + cs2[2 * wnl + 1][cl];
            int c = j0 + tid;
            atomicAdd(&stats[c], (double)t1);
            atomicAdd(&stats[H_ + c], (double)t2);
        }
    }
}

// ---- symmetric gram: D[i][j] = sq[j] - 2 <x_i, x_j>, upper-tri tile pairs only ----
// 1-D grid 1088: z = blk&7 (XCD pin), p = blk>>3 enumerates bi<=bj tile pairs.
// B-side reads P-pack with segment remap (0,2,1).
// Epilogue: wave-private LDS transpose (separate array; VGPR 84, measured best)
// -> all stores f32x4 NT with contiguous 64B runs per row.
__global__ __launch_bounds__(256) void gram_sym(const ushort_t* __restrict__ Ap,
                                                const float* __restrict__ sqb,
                                                float* __restrict__ D) {
    __shared__ __align__(16) ushort_t As[128 * 32];
    __shared__ __align__(16) ushort_t Bs[128 * 32];
    __shared__ __align__(16) float stg[4][1280];   // wave-private transpose pool
    int blk = blockIdx.x;
    int z = blk & 7;
    int p = blk >> 3;
    int bi = 0, rem = p;
    while (rem >= 16 - bi) { rem -= 16 - bi; ++bi; }
    int bj = bi + rem;
    const ushort_t* Pz = Ap + (size_t)z * N_ * KP_;
    const float* sqz = sqb + (size_t)z * N_;
    float* Dz = D + (size_t)z * N_ * N_;
    int i0 = bi * 128, j0 = bj * 128;

    int tid = threadIdx.x;
    int lane = tid & 63, wave = tid >> 6;
    int wm = wave & 1, wn = wave >> 1;
    int m16 = lane & 15, q4 = lane >> 4;
    int kq = q4 * 8;

    f32x4 acc[4][4];
    f32x4 zero = {0.f, 0.f, 0.f, 0.f};
#pragma unroll
    for (int i = 0; i < 4; ++i)
#pragma unroll
        for (int j = 0; j < 4; ++j) acc[i][j] = zero;

    int srow = tid >> 2;
    int skc  = (tid & 3) * 8;

    for (int k0 = 0; k0 < KP_; k0 += 32) {
        // Q segment remap: seg0->seg0(hi), seg1->seg2(hi), seg2->seg1(lo)
        int kb = (k0 < 256) ? k0 : ((k0 < 512) ? k0 + 256 : k0 - 256);
#pragma unroll
        for (int s = 0; s < 2; ++s) {
            int row = srow + s * 64;
            const ushort_t* gpA = Pz + (size_t)(i0 + row) * KP_ + k0 + skc;
            const ushort_t* gpB = Pz + (size_t)(j0 + row) * KP_ + kb + skc;
            __builtin_amdgcn_global_load_lds(
                (const __attribute__((address_space(1))) void*)gpA,
                (__attribute__((address_space(3))) void*)(As + (size_t)(wave * 64 + s * 256) * 8),
                16, 0, 0);
            __builtin_amdgcn_global_load_lds(
                (const __attribute__((address_space(1))) void*)gpB,
                (__attribute__((address_space(3))) void*)(Bs + (size_t)(wave * 64 + s * 256) * 8),
                16, 0, 0);
        }
        __syncthreads();
        short8 af[4], bfr[4];
#pragma unroll
        for (int fi = 0; fi < 4; ++fi)
            af[fi] = *(const short8*)(As + (wm * 64 + fi * 16 + m16) * 32 + kq);
#pragma unroll
        for (int fj = 0; fj < 4; ++fj)
            bfr[fj] = *(const short8*)(Bs + (wn * 64 + fj * 16 + m16) * 32 + kq);
#pragma unroll
        for (int fi = 0; fi < 4; ++fi)
#pragma unroll
            for (int fj = 0; fj < 4; ++fj)
                acc[fi][fj] = __builtin_amdgcn_mfma_f32_16x16x32_bf16(
                    af[fi], bfr[fj], acc[fi][fj], 0, 0, 0);
        __syncthreads();
    }

    float* sg = stg[wave];
    float scl[4];
#pragma unroll
    for (int fj = 0; fj < 4; ++fj) scl[fj] = sqz[j0 + wn * 64 + fj * 16 + m16];
    float sr[4][4];
#pragma unroll
    for (int fi = 0; fi < 4; ++fi) {
        float4 s4 = *(const float4*)(sqz + i0 + wm * 64 + fi * 16 + q4 * 4);
        sr[fi][0] = s4.x; sr[fi][1] = s4.y; sr[fi][2] = s4.z; sr[fi][3] = s4.w;
    }

    // normal orientation: per fi, wave-private [16][68] transpose -> f32x4 stores
    int rr = lane >> 2, cc = lane & 3;
#pragma unroll
    for (int fi = 0; fi < 4; ++fi) {
#pragma unroll
        for (int fj = 0; fj < 4; ++fj)
#pragma unroll
            for (int r = 0; r < 4; ++r)
                sg[(q4 * 4 + r) * 68 + fj * 16 + m16] = scl[fj] - 2.f * acc[fi][fj][r];
        float* drow = Dz + (size_t)(i0 + wm * 64 + fi * 16 + rr) * N_ + j0 + wn * 64;
#pragma unroll
        for (int t = 0; t < 4; ++t) {
            int chunk = cc + 4 * t;
            f32x4 o = *(const f32x4*)(sg + rr * 68 + chunk * 4);
            __builtin_nontemporal_store(o, (f32x4*)(drow + chunk * 4));
        }
    }

    // transposed orientation (off-diag): per fi, wave-private [64][20] -> f32x4 stores
    if (bi != bj) {
#pragma unroll
        for (int fi = 0; fi < 4; ++fi) {
#pragma unroll
            for (int fj = 0; fj < 4; ++fj)
#pragma unroll
                for (int r = 0; r < 4; ++r)
                    sg[(fj * 16 + m16) * 20 + q4 * 4 + r] =
                        sr[fi][r] - 2.f * acc[fi][fj][r];
            int chunk = lane & 3;
#pragma unroll
            for (int u = 0; u < 4; ++u) {
                int cr = (lane >> 2) + 16 * u;
                f32x4 o = *(const f32x4*)(sg + cr * 20 + chunk * 4);
                __builtin_nontemporal_store(o,
                    (f32x4*)(Dz + (size_t)(j0 + wn * 64 + cr) * N_ +
                             i0 + wm * 64 + fi * 16 + chunk * 4));
            }
        }
    }
}

// ---- threshold top-16 smallest per row (exact, lex (value,col) tie-break) ----
__global__ __launch_bounds__(256) void topk16(const float* __restrict__ D,
                                              int* __restrict__ idxb) {
    __shared__ unsigned long long cand[4][256];
    __shared__ int cnt[4];
    int w = threadIdx.x >> 6, lane = threadIdx.x & 63;
    int row = blockIdx.x * 4 + w;
    const float* dp = D + (size_t)row * N_;
    unsigned sk[32];
#pragma unroll
    for (int t = 0; t < 8; ++t) {
        f32x4 v4 = __builtin_nontemporal_load((const f32x4*)(dp + t * 256 + lane * 4));
#pragma unroll
        for (int j = 0; j < 4; ++j) {
            unsigned u = __float_as_uint(v4[j]);
            sk[t * 4 + j] = (u & 0x80000000u) ? ~u : (u | 0x80000000u);
        }
    }
    if (lane == 0) cnt[w] = 0;
    unsigned vm = sk[0];
#pragma unroll
    for (int i = 1; i < 32; ++i) vm = min(vm, sk[i]);
#pragma unroll
    for (int k = 2; k <= 64; k <<= 1) {
#pragma unroll
        for (int j = k >> 1; j > 0; j >>= 1) {
            unsigned pv = __shfl_xor(vm, j);
            bool up = ((lane & k) == 0);
            bool lower = ((lane & j) == 0);
            unsigned mn = min(vm, pv), mx = max(vm, pv);
            vm = (lower == up) ? mn : mx;
        }
    }
    unsigned T = __shfl(vm, 15);   // 16th smallest lane-min >= 16th order statistic
    __syncthreads();
#pragma unroll
    for (int i = 0; i < 32; ++i) {
        if (sk[i] <= T) {
            unsigned col = (unsigned)((i >> 2) * 256 + lane * 4 + (i & 3));
            int s = atomicAdd(&cnt[w], 1);
            if (s < 256) cand[w][s] = ((unsigned long long)sk[i] << 32) | col;
        }
    }
    __syncthreads();
    int cn = cnt[w];
    if (cn <= 64) {
        unsigned long long mykey = (lane < cn) ? cand[w][lane] : ~0ull;
        for (int it = 0; it < 16; ++it) {
            unsigned long long best = mykey;
#pragma unroll
            for (int off = 32; off; off >>= 1) {
                unsigned long long o = __shfl_xor(best, off);
                if (o < best) best = o;
            }
            if (mykey == best) mykey = ~0ull;
            if (lane == 0) idxb[row * 16 + it] = (int)(unsigned)(best & 0xffffffffu);
        }
    } else if (cn <= 256) {
        for (int it = 0; it < 16; ++it) {
            unsigned long long best = ~0ull;
            for (int i = lane; i < cn; i += 64) {
                unsigned long long c = cand[w][i];
                if (c < best) best = c;
            }
#pragma unroll
            for (int off = 32; off; off >>= 1) {
                unsigned long long o = __shfl_xor(best, off);
                if (o < best) best = o;
            }
            for (int i = lane; i < cn; i += 64)
                if (cand[w][i] == best) cand[w][i] = ~0ull;
            if (lane == 0) idxb[row * 16 + it] = (int)(unsigned)(best & 0xffffffffu);
        }
    } else {
        unsigned mask = 0;
        for (int it = 0; it < 16; ++it) {
            unsigned long long key = ~0ull;
#pragma unroll
            for (int i = 0; i < 32; ++i) {
                if (!((mask >> i) & 1u)) {
                    unsigned long long k2 = ((unsigned long long)sk[i] << 32) |
                        (unsigned)((i >> 2) * 256 + lane * 4 + (i & 3));
                    if (k2 < key) key = k2;
                }
            }
#pragma unroll
            for (int off = 32; off; off >>= 1) {
                unsigned long long o = __shfl_xor(key, off);
                if (o < key) key = o;
            }
            unsigned jc = (unsigned)(key & 0xffffffffu);
            int li = ((jc & 255) >> 2);
            int ii = ((jc >> 8) << 2) | (jc & 3);
            if (lane == li) mask |= 1u << ii;
            if (lane == 0) idxb[row * 16 + it] = (int)jc;
        }
    }
}

// t[b,i,h] = uv[row][h] + max_k uv[(b,idx_k)][256+h]; accumulates BN stats of t.
// XCD-pinned: z = blk&7 -> each XCD gathers within its own batch's 2 MB v-half.
__global__ void gather_max(const float* __restrict__ uv, const int* __restrict__ idxb,
                           float* __restrict__ outp, double* __restrict__ stats) {
    int blk = blockIdx.x;
    int b = blk & 7;
    int strip = blk >> 3;               // 0..63
    int r0 = b * N_ + strip * 32;
    int f = threadIdx.x;
    float s1 = 0.f, s2 = 0.f;
    for (int rr = 0; rr < 32; ++rr) {
        int row = r0 + rr;
        const int* ip = idxb + row * 16;
        float m = -FLT_MAX;
#pragma unroll
        for (int k = 0; k < 16; ++k) {
            int j = ip[k];
            m = fmaxf(m, uv[((size_t)((b << 11) + j)) * 512 + 256 + f]);
        }
        float v = uv[(size_t)row * 512 + f] + m;
        outp[(size_t)row * H_ + f] = v;
        s1 += v; s2 += v * v;
    }
    atomicAdd(&stats[f], (double)s1);
    atomicAdd(&stats[H_ + f], (double)s2);
}

// ---- batchnorm helpers ----
__global__ void bn_zero(double* s) { s[threadIdx.x] = 0.0; }

// reads per-feature sums, emits scale/shift, re-zeroes sums for the next user
__global__ void bn_final(double* __restrict__ sums, const float* __restrict__ g,
                         const float* __restrict__ b, float* __restrict__ scsh) {
    int f = threadIdx.x;
    double m  = sums[f] / (double)BN_;
    double var = sums[H_ + f] / (double)BN_ - m * m;
    double inv = 1.0 / sqrt(var + 1e-5);
    float sc = g[f] * (float)inv;
    scsh[f] = sc;
    scsh[H_ + f] = b[f] - (float)m * sc;
    sums[f] = 0.0; sums[H_ + f] = 0.0;
}

// BN+ReLU fused with split-bf16 packing and (optional) row sqnorm reduce.
// Vectorized: one wave = 2 rows, lane owns 8 contiguous features.
__global__ void bn_apply_pack(const float* __restrict__ X, const float* __restrict__ scsh,
                              ushort_t* __restrict__ Ap, float* __restrict__ sq) {
    int tid = threadIdx.x;
    int row = blockIdx.x * 8 + (tid >> 5);
    int f0  = (tid & 31) * 8;
    const float* xp = X + (size_t)row * H_ + f0;
    f32x4 x0 = *(const f32x4*)(xp);
    f32x4 x1 = *(const f32x4*)(xp + 4);
    f32x4 sc0 = *(const f32x4*)(scsh + f0);
    f32x4 sc1 = *(const f32x4*)(scsh + f0 + 4);
    f32x4 sh0 = *(const f32x4*)(scsh + H_ + f0);
    f32x4 sh1 = *(const f32x4*)(scsh + H_ + f0 + 4);
    float v[8];
#pragma unroll
    for (int i = 0; i < 4; ++i) {
        v[i]     = fmaxf(x0[i] * sc0[i] + sh0[i], 0.f);
        v[i + 4] = fmaxf(x1[i] * sc1[i] + sh1[i], 0.f);
    }
    short8 hi8, lo8;
#pragma unroll
    for (int i = 0; i < 8; ++i) {
        ushort_t hi = f2bf(v[i]);
        ushort_t lo = f2bf(v[i] - bf2f(hi));
        hi8[i] = (short)hi; lo8[i] = (short)lo;
    }
    ushort_t* ap = Ap + (size_t)row * KP_ + f0;
    *(short8*)(ap)            = hi8;
    *(short8*)(ap + H_)       = lo8;
    *(short8*)(ap + 2 * H_)   = hi8;
    if (sq) {
        float s = 0.f;
#pragma unroll
        for (int i = 0; i < 8; ++i) s += v[i] * v[i];
#pragma unroll
        for (int off = 16; off; off >>= 1) s += __shfl_down(s, off, 32);
        if ((tid & 31) == 0) sq[row] = s;
    }
}

__global__ void maxpool1(const float* __restrict__ y, float* __restrict__ pmax) {
    int b = blockIdx.x, gc = blockIdx.y, nc = blockIdx.z;
    int g = gc * 256 + threadIdx.x;
    const float* yb = y + ((size_t)b * N_ + (size_t)nc * 128) * G_;
    float m = -FLT_MAX;
    for (int n = 0; n < 128; ++n) m = fmaxf(m, yb[(size_t)n * G_ + g]);
    pmax[((size_t)(b * 16 + nc)) * G_ + g] = m;
}

__global__ void maxpool2(const float* __restrict__ pmax, float* __restrict__ p) {
    int b = blockIdx.x;
    int g = blockIdx.y * 256 + threadIdx.x;
    float m = -FLT_MAX;
    for (int c = 0; c < 16; ++c) m = fmaxf(m, pmax[((size_t)(b * 16 + c)) * G_ + g]);
    p[(size_t)b * G_ + g] = m;
}

// parallel split-K head gemm: grid(M, Nd/64), 256 thr = 64 cols x 4 k-slices
__global__ __launch_bounds__(256) void head_gemm(const float* __restrict__ A,
                                                 const float* __restrict__ W,
                                                 const float* __restrict__ bias,
                                                 float* __restrict__ Cc,
                                                 int Kd, int Nd, int relu) {
    int m = blockIdx.x;
    int c0 = blockIdx.y * 64;
    int cl = threadIdx.x & 63;
    int ks = threadIdx.x >> 6;
    int kper = Kd >> 2;
    const float* Ap = A + (size_t)m * Kd + (size_t)ks * kper;
    const float* Wp = W + (size_t)ks * kper * Nd + c0 + cl;
    float acc = 0.f;
    for (int k = 0; k < kper; k += 8) {
#pragma unroll
        for (int u2 = 0; u2 < 8; ++u2)
            acc += Ap[k + u2] * Wp[(size_t)(k + u2) * Nd];
    }
    __shared__ float red[4][64];
    red[ks][cl] = acc;
    __syncthreads();
    if (ks == 0) {
        float s = red[0][cl] + red[1][cl] + red[2][cl] + red[3][cl] + bias[c0 + cl];
        if (relu) s = fmaxf(s, 0.f);
        Cc[(size_t)m * Nd + c0 + cl] = s;
    }
}

// ---------------- launch ----------------
extern "C" void kernel_launch(void* const* d_in, const int* in_sizes, int n_in,
                              void* d_out, int out_size, void* d_ws, size_t ws_size,
                              hipStream_t stream) {
    (void)in_sizes; (void)n_in; (void)out_size;
    if (ws_size < WS_NEEDED) return;

    const float* x    = (const float*)d_in[0];
    const float* Wf   = (const float*)d_in[2];
    const float* bfv  = (const float*)d_in[3];
    const float* Wnn  = (const float*)d_in[4];
    const float* bnn  = (const float*)d_in[5];
    const float* g1   = (const float*)d_in[6];
    const float* b1   = (const float*)d_in[7];
    const float* We   = (const float*)d_in[8];
    const float* be   = (const float*)d_in[9];
    const float* g2   = (const float*)d_in[10];
    const float* b2   = (const float*)d_in[11];
    const float* Wl   = (const float*)d_in[12];
    const float* bl   = (const float*)d_in[13];
    const float* alpha= (const float*)d_in[14];
    const float* gg   = (const float*)d_in[15];
    const float* bgb  = (const float*)d_in[16];
    const float* Wg   = (const float*)d_in[17];
    const float* bg2  = (const float*)d_in[18];
    const float* Wm1  = (const float*)d_in[19];
    const float* bm1  = (const float*)d_in[20];
    const float* Wm2  = (const float*)d_in[21];
    const float* bm2  = (const float*)d_in[22];
    const float* Wm3  = (const float*)d_in[23];
    const float* bm3  = (const float*)d_in[24];
    float* outp = (float*)d_out;

    char* ws = (char*)d_ws;
    float*    h    = (float*)(ws + OFF_H);
    ushort_t* Ap   = (ushort_t*)(ws + OFF_APACK);
    float*    sqb  = (float*)(ws + OFF_SQ);
    int*      idxb = (int*)  (ws + OFF_IDX);
    double*   stats= (double*)(ws + OFF_STATS);
    float*    scsh = (float*)(ws + OFF_SCSH);
    float*    bcat = (float*)(ws + OFF_BCAT);
    float*    p0   = (float*)(ws + OFF_P0);
    float*    p1   = (float*)(ws + OFF_P1);
    float*    p2   = (float*)(ws + OFF_P2);
    float*    dmat = (float*)(ws + OFF_D);
    float*    t    = (float*)(ws + OFF_T);
    float*    uv   = (float*)(ws + OFF_UV);
    float*    y    = (float*)(ws + OFF_UV);
    ushort_t* Qw   = (ushort_t*)(ws + OFF_QW);
    float*    pmax = (float*)(ws + OFF_PMAX);

    // one-time zero (ws is re-poisoned before every call); bn_final re-zeroes after use
    hipLaunchKernelGGL(bn_zero, dim3(1), dim3(512), 0, stream, stats);

    // h = x@Wf+bf (+pack), t = h@Wnn+bnn via MFMA (accumulates t-stats), XCD-pinned
    hipLaunchKernelGGL(feat_pack, dim3(BN_), dim3(256), 0, stream, x, Wf, bfv, h, Ap);
    hipLaunchKernelGGL(pack_wT, dim3(H_), dim3(256), 0, stream, Wnn, Qw, H_);
    hipLaunchKernelGGL(mfma_gemm, dim3(256), dim3(256), 0, stream,
                       Ap, Qw, bnn, t, KP_, H_, 0,
                       (const float*)nullptr, (const float*)nullptr, 0, stats, 2);

    for (int l = 0; l < L_; ++l) {
        const float* src1 = (l == 0) ? t : h;
        hipLaunchKernelGGL(bn_final, dim3(1), dim3(256), 0, stream,
                           stats, g1 + l * H_, b1 + l * H_, scsh);
        hipLaunchKernelGGL(bn_apply_pack, dim3(BN_ / 8), dim3(256), 0, stream,
                           src1, scsh, Ap, sqb);
        // symmetric gram -> D (both triangles written, upper computed), XCD-pinned
        hipLaunchKernelGGL(gram_sym, dim3(1088), dim3(256), 0, stream,
                           Ap, sqb, dmat);
        hipLaunchKernelGGL(topk16, dim3(BN_ / 4), dim3(256), 0, stream, dmat, idxb);
        // fused u|v gemm (N=512), XCD-pinned
        hipLaunchKernelGGL(pack_qcat, dim3(512), dim3(256), 0, stream,
                           We + (size_t)l * 2 * H_ * H_, be + (size_t)l * H_, Qw, bcat);
        hipLaunchKernelGGL(mfma_gemm, dim3(512), dim3(256), 0, stream,
                           Ap, Qw, bcat, uv, KP_, 512, 0,
                           (const float*)nullptr, (const float*)nullptr, 0,
                           (double*)nullptr, 4);
        hipLaunchKernelGGL(gather_max, dim3(512), dim3(256), 0, stream,
                           uv, idxb, t, stats);
        // BN2 + Wl with fused residual: h = h + alpha[l]*(xb@Wl + bl) (+h-stats)
        hipLaunchKernelGGL(bn_final, dim3(1), dim3(256), 0, stream,
                           stats, g2 + l * H_, b2 + l * H_, scsh);
        hipLaunchKernelGGL(bn_apply_pack, dim3(BN_ / 8), dim3(256), 0, stream,
                           t, scsh, Ap, (float*)nullptr);
        hipLaunchKernelGGL(pack_wT, dim3(H_), dim3(256), 0, stream,
                           Wl + (size_t)l * H_ * H_, Qw, H_);
        hipLaunchKernelGGL(mfma_gemm, dim3(256), dim3(256), 0, stream,
                           Ap, Qw, bl + (size_t)l * H_, h, KP_, H_, 2,
                           h, alpha, l, stats, 2);
    }

    // head
    hipLaunchKernelGGL(bn_final, dim3(1), dim3(256), 0, stream, stats, gg, bgb, scsh);
    hipLaunchKernelGGL(bn_apply_pack, dim3(BN_ / 8), dim3(256), 0, stream,
                       h, scsh, Ap, (float*)nullptr);
    hipLaunchKernelGGL(pack_wT, dim3(G_), dim3(256), 0, stream, Wg, Qw, G_);
    hipLaunchKernelGGL(mfma_gemm, dim3(512), dim3(256), 0, stream,
                       Ap, Qw, bg2, y, KP_, G_, 0,
                       (const float*)nullptr, (const float*)nullptr, 0,
                       (double*)nullptr, 4);
    hipLaunchKernelGGL(maxpool1, dim3(8, 2, 16), dim3(256), 0, stream, y, pmax);
    hipLaunchKernelGGL(maxpool2, dim3(8, 2), dim3(256), 0, stream, pmax, p0);
    hipLaunchKernelGGL(head_gemm, dim3(8, 4), dim3(256), 0, stream, p0, Wm1, bm1, p1, G_, M0_, 1);
    hipLaunchKernelGGL(head_gemm, dim3(8, 2), dim3(256), 0, stream, p1, Wm2, bm2, p2, M0_, M1_, 1);
    hipLaunchKernelGGL(head_gemm, dim3(8, 2), dim3(256), 0, stream, p2, Wm3, bm3, outp, M1_, C_, 0);
}